// Round 1
// baseline (87.604 us; speedup 1.0000x reference)
//
#include <hip/hip_runtime.h>
#include <hip/hip_bf16.h>

// Problem constants (match reference)
#define B_ 2
#define N_ 1024
#define M_ 1024
#define H_ 128
// SCALE = 1 / 128^0.4
#define SCALE_F 0.14358729f

// Kernel A: per-batch softmax weights p[b,m] = softmax_m(SCALE * k[b,m,:]·colsum(W))
// Grid = B_ blocks, 1024 threads (one thread per m).
__global__ void __launch_bounds__(1024) softmax_p_kernel(
    const float* __restrict__ keys,   // [B, M, H]
    const float* __restrict__ W,      // [H, H] row-major, W[o*H + h]
    float* __restrict__ p)            // [B, M] out
{
    const int b = blockIdx.x;
    const int m = threadIdx.x;            // 0..1023
    __shared__ float wsum[H_];
    __shared__ float red[16];
    __shared__ float bc[2];

    // colsum over rows o of W: wsum[h] = sum_o W[o,h]  (coalesced: consecutive h)
    if (m < H_) {
        float s = 0.f;
        #pragma unroll 8
        for (int o = 0; o < H_; ++o) s += W[o * H_ + m];
        wsum[m] = s;
    }
    __syncthreads();

    // logit = SCALE * dot(keys[b,m,:], wsum)
    const float4* krow = (const float4*)(keys + ((size_t)b * M_ + m) * H_);
    const float4* w4   = (const float4*)wsum;   // same-address per iter -> LDS broadcast
    float acc = 0.f;
    #pragma unroll
    for (int i = 0; i < H_ / 4; ++i) {
        float4 k4 = krow[i];
        float4 ww = w4[i];
        acc = fmaf(k4.x, ww.x, acc);
        acc = fmaf(k4.y, ww.y, acc);
        acc = fmaf(k4.z, ww.z, acc);
        acc = fmaf(k4.w, ww.w, acc);
    }
    const float logit = SCALE_F * acc;

    const int lane = m & 63;
    const int wid  = m >> 6;      // 16 waves

    // ---- block max ----
    float v = logit;
    #pragma unroll
    for (int off = 32; off > 0; off >>= 1) v = fmaxf(v, __shfl_down(v, off));
    if (lane == 0) red[wid] = v;
    __syncthreads();
    if (wid == 0) {
        float t = (lane < 16) ? red[lane] : -3.4e38f;
        #pragma unroll
        for (int off = 8; off > 0; off >>= 1) t = fmaxf(t, __shfl_down(t, off));
        if (lane == 0) bc[0] = t;
    }
    __syncthreads();
    const float gmax = bc[0];
    const float e = __expf(logit - gmax);
    __syncthreads();   // red reuse

    // ---- block sum ----
    v = e;
    #pragma unroll
    for (int off = 32; off > 0; off >>= 1) v += __shfl_down(v, off);
    if (lane == 0) red[wid] = v;
    __syncthreads();
    if (wid == 0) {
        float t = (lane < 16) ? red[lane] : 0.f;
        #pragma unroll
        for (int off = 8; off > 0; off >>= 1) t += __shfl_down(t, off);
        if (lane == 0) bc[1] = 1.0f / t;
    }
    __syncthreads();

    p[b * M_ + m] = e * bc[1];
}

// Kernel B: out[b,n,m] = p[b,m] * values[b,n], vectorized float4 over m.
// Total float4 elements: B*N*M/4 = 524288. Grid 2048 x 256.
__global__ void __launch_bounds__(256) outer_write_kernel(
    const float* __restrict__ p,      // [B, M]
    const float* __restrict__ values, // [B, N] (flattened [B,N,1,1])
    float4* __restrict__ out)         // [B, N, M] as float4
{
    const int j  = blockIdx.x * blockDim.x + threadIdx.x;  // 0 .. B*N*M/4-1
    const int m4 = j & (M_ / 4 - 1);           // & 255
    const int n  = (j >> 8) & (N_ - 1);        // >>log2(M/4), & 1023
    const int b  = j >> 18;                    // / (N*M/4) = / 262144

    const float4 pv = ((const float4*)p)[(b << 8) + m4];  // L2-resident, coalesced
    const float  v  = values[(b << 10) + n];              // broadcast within wave
    float4 o;
    o.x = pv.x * v; o.y = pv.y * v; o.z = pv.z * v; o.w = pv.w * v;
    out[j] = o;
}

extern "C" void kernel_launch(void* const* d_in, const int* in_sizes, int n_in,
                              void* d_out, int out_size, void* d_ws, size_t ws_size,
                              hipStream_t stream) {
    // inputs: 0=queries (unused!), 1=keys, 2=values, 3=W, 4=b (cancels in softmax)
    const float* keys   = (const float*)d_in[1];
    const float* values = (const float*)d_in[2];
    const float* W      = (const float*)d_in[3];
    float* out = (float*)d_out;
    float* p   = (float*)d_ws;   // B*M floats = 8 KB scratch

    softmax_p_kernel<<<B_, 1024, 0, stream>>>(keys, W, p);

    const int total4 = B_ * N_ * M_ / 4;   // 524288
    outer_write_kernel<<<total4 / 256, 256, 0, stream>>>(p, values, (float4*)out);
}

// Round 2
// 84.595 us; speedup vs baseline: 1.0356x; 1.0356x over previous
//
#include <hip/hip_runtime.h>
#include <hip/hip_bf16.h>

// Problem constants (match reference)
#define B_ 2
#define N_ 1024
#define M_ 1024
#define H_ 128
// SCALE = 1 / 128^0.4
#define SCALE_F 0.14358729f

// Kernel A: per-batch softmax weights p[b,m] = softmax_m(SCALE * k[b,m,:]·colsum(W))
// Grid = B_ blocks, 1024 threads (one thread per m).
// Math note: qp-row-sums and bias-sum are constant over the softmax axis and
// cancel exactly; queries are never needed.
__global__ void __launch_bounds__(1024) softmax_p_kernel(
    const float* __restrict__ keys,   // [B, M, H]
    const float* __restrict__ W,      // [H, H] row-major, W[o*H + h]
    float* __restrict__ p)            // [B, M] out
{
    const int b = blockIdx.x;
    const int m = threadIdx.x;            // 0..1023
    __shared__ float wpart[8][H_];        // row-group partial colsums
    __shared__ float wsum[H_];
    __shared__ float red[16];
    __shared__ float bc[2];

    // colsum over rows o of W, parallelized over all 1024 threads:
    // thread (grp,col) sums 16 rows; 16 independent loads -> single latency hit.
    {
        const int col = m & (H_ - 1);     // 0..127
        const int grp = m >> 7;           // 0..7
        float s = 0.f;
        #pragma unroll
        for (int i = 0; i < 16; ++i)
            s += W[(grp * 16 + i) * H_ + col];
        wpart[grp][col] = s;
    }
    __syncthreads();
    if (m < H_) {
        float t = 0.f;
        #pragma unroll
        for (int g = 0; g < 8; ++g) t += wpart[g][m];
        wsum[m] = t;
    }
    __syncthreads();

    // logit = SCALE * dot(keys[b,m,:], wsum)
    const float4* krow = (const float4*)(keys + ((size_t)b * M_ + m) * H_);
    const float4* w4   = (const float4*)wsum;   // same-address per iter -> LDS broadcast
    float acc = 0.f;
    #pragma unroll
    for (int i = 0; i < H_ / 4; ++i) {
        float4 k4 = krow[i];
        float4 ww = w4[i];
        acc = fmaf(k4.x, ww.x, acc);
        acc = fmaf(k4.y, ww.y, acc);
        acc = fmaf(k4.z, ww.z, acc);
        acc = fmaf(k4.w, ww.w, acc);
    }
    const float logit = SCALE_F * acc;

    const int lane = m & 63;
    const int wid  = m >> 6;      // 16 waves

    // ---- block max ----
    float v = logit;
    #pragma unroll
    for (int off = 32; off > 0; off >>= 1) v = fmaxf(v, __shfl_down(v, off));
    if (lane == 0) red[wid] = v;
    __syncthreads();
    if (wid == 0) {
        float t = (lane < 16) ? red[lane] : -3.4e38f;
        #pragma unroll
        for (int off = 8; off > 0; off >>= 1) t = fmaxf(t, __shfl_down(t, off));
        if (lane == 0) bc[0] = t;
    }
    __syncthreads();
    const float gmax = bc[0];
    const float e = __expf(logit - gmax);
    __syncthreads();   // red reuse

    // ---- block sum ----
    v = e;
    #pragma unroll
    for (int off = 32; off > 0; off >>= 1) v += __shfl_down(v, off);
    if (lane == 0) red[wid] = v;
    __syncthreads();
    if (wid == 0) {
        float t = (lane < 16) ? red[lane] : 0.f;
        #pragma unroll
        for (int off = 8; off > 0; off >>= 1) t += __shfl_down(t, off);
        if (lane == 0) bc[1] = 1.0f / t;
    }
    __syncthreads();

    p[b * M_ + m] = e * bc[1];
}

// Kernel B: out[b,n,m] = p[b,m] * values[b,n], vectorized float4 over m.
// Total float4 elements: B*N*M/4 = 524288. Grid 2048 x 256. Write-BW bound
// (8 MB -> ~1.3 us floor); p/values are L2/L1-resident.
__global__ void __launch_bounds__(256) outer_write_kernel(
    const float* __restrict__ p,      // [B, M]
    const float* __restrict__ values, // [B, N] (flattened [B,N,1,1])
    float4* __restrict__ out)         // [B, N, M] as float4
{
    const int j  = blockIdx.x * blockDim.x + threadIdx.x;  // 0 .. B*N*M/4-1
    const int m4 = j & (M_ / 4 - 1);           // & 255
    const int n  = (j >> 8) & (N_ - 1);        // >>log2(M/4), & 1023
    const int b  = j >> 18;                    // / (N*M/4) = / 262144

    const float4 pv = ((const float4*)p)[(b << 8) + m4];  // L2-resident, coalesced
    const float  v  = values[(b << 10) + n];              // broadcast within wave
    float4 o;
    o.x = pv.x * v; o.y = pv.y * v; o.z = pv.z * v; o.w = pv.w * v;
    out[j] = o;
}

extern "C" void kernel_launch(void* const* d_in, const int* in_sizes, int n_in,
                              void* d_out, int out_size, void* d_ws, size_t ws_size,
                              hipStream_t stream) {
    // inputs: 0=queries (unused!), 1=keys, 2=values, 3=W, 4=b (cancels in softmax)
    const float* keys   = (const float*)d_in[1];
    const float* values = (const float*)d_in[2];
    const float* W      = (const float*)d_in[3];
    float* out = (float*)d_out;
    float* p   = (float*)d_ws;   // B*M floats = 8 KB scratch

    softmax_p_kernel<<<B_, 1024, 0, stream>>>(keys, W, p);

    const int total4 = B_ * N_ * M_ / 4;   // 524288
    outer_write_kernel<<<total4 / 256, 256, 0, stream>>>(p, values, (float4*)out);
}